// Round 17
// baseline (2102.764 us; speedup 1.0000x reference)
//
#include <hip/hip_runtime.h>
#include <stdint.h>

#define T_STEPS 784
#define H 256
#define NBLK 256        // 2 samples per block, target 2 blocks/CU
#define NTHR 256        // 4 waves; wave w owns rows AND neurons [64w, 64w+64)

typedef unsigned long long u64;

// Per-neuron mask parameters, replicating numpy linspace/ceil/round in float64.
__device__ __forceinline__ void mask_params(int j, int& c, int& on, int& ps) {
    const double stepc = (8.0 - 4.0) / 255.0;
    const double stepd = (0.9 - 0.1) / 255.0;
    const double stepp = 4.0 / 255.0;
    double cyc = (j == 255) ? 8.0 : __dadd_rn(__dmul_rn((double)j, stepc), 4.0);
    c = (int)ceil(cyc);
    double dc  = (j == 255) ? 0.9 : __dadd_rn(__dmul_rn((double)j, stepd), 0.1);
    on = (int)ceil(__dmul_rn(dc, (double)c));
    double psd = (j == 255) ? 4.0 : __dmul_rn((double)j, stepp);
    ps = (int)rint(psd);
}

__device__ __forceinline__ void fmac4(float4& a, float f, const float4& w) {
    a.x = fmaf(f, w.x, a.x); a.y = fmaf(f, w.y, a.y);
    a.z = fmaf(f, w.z, a.z); a.w = fmaf(f, w.w, a.w);
}

#define SELF(m,k) ((((m) >> (k)) & 1ull) ? 1.0f : 0.0f)

// Union 2-sample paired consume: one union mask drives TWO matrices; each
// loaded row is applied to BOTH samples via SGPR-select fmacs (f in {0,1};
// fmaf(0,w,a)==a exactly). Straight-line 16-load batches; binary tail.
#define APPLY2(ki, xi, yi)                                         \
    {   float f0 = SELF(m0, ki), f1 = SELF(m1, ki);                \
        fmac4(aX0, f0, xi); fmac4(aX1, f1, xi);                    \
        fmac4(aY0, f0, yi); fmac4(aY1, f1, yi); }

__device__ __forceinline__ void consume_pair_2s(const char* __restrict__ bX,
                                                const char* __restrict__ bY,
                                                u64 m0, u64 m1, int l16,
                                                float4& aX0, float4& aX1,
                                                float4& aY0, float4& aY1) {
    u64 u = m0 | m1;
    int n = __popcll(u);
    while (n >= 8) {
        int k0=__builtin_ctzll(u); u&=u-1; int k1=__builtin_ctzll(u); u&=u-1;
        int k2=__builtin_ctzll(u); u&=u-1; int k3=__builtin_ctzll(u); u&=u-1;
        int k4=__builtin_ctzll(u); u&=u-1; int k5=__builtin_ctzll(u); u&=u-1;
        int k6=__builtin_ctzll(u); u&=u-1; int k7=__builtin_ctzll(u); u&=u-1;
        float4 x0 = *(const float4*)(bX + (k0<<10) + l16);
        float4 x1 = *(const float4*)(bX + (k1<<10) + l16);
        float4 x2 = *(const float4*)(bX + (k2<<10) + l16);
        float4 x3 = *(const float4*)(bX + (k3<<10) + l16);
        float4 x4 = *(const float4*)(bX + (k4<<10) + l16);
        float4 x5 = *(const float4*)(bX + (k5<<10) + l16);
        float4 x6 = *(const float4*)(bX + (k6<<10) + l16);
        float4 x7 = *(const float4*)(bX + (k7<<10) + l16);
        float4 y0 = *(const float4*)(bY + (k0<<10) + l16);
        float4 y1 = *(const float4*)(bY + (k1<<10) + l16);
        float4 y2 = *(const float4*)(bY + (k2<<10) + l16);
        float4 y3 = *(const float4*)(bY + (k3<<10) + l16);
        float4 y4 = *(const float4*)(bY + (k4<<10) + l16);
        float4 y5 = *(const float4*)(bY + (k5<<10) + l16);
        float4 y6 = *(const float4*)(bY + (k6<<10) + l16);
        float4 y7 = *(const float4*)(bY + (k7<<10) + l16);
        APPLY2(k0, x0, y0); APPLY2(k1, x1, y1);
        APPLY2(k2, x2, y2); APPLY2(k3, x3, y3);
        APPLY2(k4, x4, y4); APPLY2(k5, x5, y5);
        APPLY2(k6, x6, y6); APPLY2(k7, x7, y7);
        n -= 8;
    }
    if (n & 4) {
        int k0=__builtin_ctzll(u); u&=u-1; int k1=__builtin_ctzll(u); u&=u-1;
        int k2=__builtin_ctzll(u); u&=u-1; int k3=__builtin_ctzll(u); u&=u-1;
        float4 x0 = *(const float4*)(bX + (k0<<10) + l16);
        float4 x1 = *(const float4*)(bX + (k1<<10) + l16);
        float4 x2 = *(const float4*)(bX + (k2<<10) + l16);
        float4 x3 = *(const float4*)(bX + (k3<<10) + l16);
        float4 y0 = *(const float4*)(bY + (k0<<10) + l16);
        float4 y1 = *(const float4*)(bY + (k1<<10) + l16);
        float4 y2 = *(const float4*)(bY + (k2<<10) + l16);
        float4 y3 = *(const float4*)(bY + (k3<<10) + l16);
        APPLY2(k0, x0, y0); APPLY2(k1, x1, y1);
        APPLY2(k2, x2, y2); APPLY2(k3, x3, y3);
    }
    if (n & 2) {
        int k0=__builtin_ctzll(u); u&=u-1; int k1=__builtin_ctzll(u); u&=u-1;
        float4 x0 = *(const float4*)(bX + (k0<<10) + l16);
        float4 x1 = *(const float4*)(bX + (k1<<10) + l16);
        float4 y0 = *(const float4*)(bY + (k0<<10) + l16);
        float4 y1 = *(const float4*)(bY + (k1<<10) + l16);
        APPLY2(k0, x0, y0); APPLY2(k1, x1, y1);
    }
    if (n & 1) {
        int k0 = __builtin_ctzll(u);
        float4 x0 = *(const float4*)(bX + (k0<<10) + l16);
        float4 y0 = *(const float4*)(bY + (k0<<10) + l16);
        APPLY2(k0, x0, y0);
    }
}

__device__ __forceinline__ void upd(float& mem, float& sp, float h, int mbit) {
    float nm = fmaf(mem * 0.5f, (1.0f - sp), h);
    mem = mbit ? nm : mem;
    sp  = (mbit && (mem > 0.5f)) ? 1.0f : 0.0f;
}

// Tiled transpose of the 4 weight matrices into ws: WT[k][j] = W[j][k].
__global__ __launch_bounds__(256)
void prep_transpose(const float* __restrict__ w1, const float* __restrict__ w2a,
                    const float* __restrict__ w2b, const float* __restrict__ w3,
                    float* __restrict__ ws)
{
    __shared__ float tile[64][65];
    const int bid = blockIdx.x;                 // 64 blocks: m(4) x kt(4) x jt(4)
    const int m  = bid >> 4;
    const int kt = (bid >> 2) & 3;
    const int jt = bid & 3;
    const float* src = (m == 0) ? w1 : (m == 1) ? w2a : (m == 2) ? w2b : w3;
    float* dst = ws + (size_t)m * H * H;
    const int tid = threadIdx.x;
    const int c = tid & 63, r4 = tid >> 6;
    #pragma unroll
    for (int rr = 0; rr < 16; rr++) {
        int r = r4 * 16 + rr;
        tile[r][c] = src[(size_t)(jt * 64 + r) * H + kt * 64 + c];
    }
    __syncthreads();
    #pragma unroll
    for (int rr = 0; rr < 16; rr++) {
        int r = r4 * 16 + rr;
        dst[(size_t)(kt * 64 + r) * H + jt * 64 + c] = tile[c][r];
    }
}

// Systolic slots (R12 skeleton): slot sl computes L1(sl), L2(sl-1), L3(sl-2)
// for TWO samples. Union row-fetch serves both samples. ONE barrier per slot;
// pex double-buffered by parity. x read via per-slot broadcast global loads
// (no xls staging -> LDS ~49.5 KB -> 2 blocks/CU residency).
__global__ __launch_bounds__(NTHR, 2)
void srnn_kernel(const float* __restrict__ x,
                 const float* __restrict__ w_i2h1, const float* __restrict__ b_i2h1,
                 const float* __restrict__ b_h2h1,
                 const float* __restrict__ b_i2h2, const float* __restrict__ b_h2h2,
                 const float* __restrict__ b_i2h3,
                 const float* __restrict__ w_h2o3, const float* __restrict__ b_h2o3,
                 const float* __restrict__ ws,     // WT1 | WT2a | WT2b | WT3
                 float* __restrict__ out)
{
    const int tid  = threadIdx.x;
    const int lane = tid & 63;
    const int w    = tid >> 6;         // wave id = j-group = row-group
    const int j    = tid;              // this thread's neuron (both samples)
    const int l16  = lane * 16;        // byte offset into each row (4 cols/lane)
    const int s0   = blockIdx.x * 2;   // first of this block's two samples

    // Wave's row-slice base per matrix: rows [64w, 64w+64), 64KB per slice.
    const char* wt1  = (const char*)ws + (0 << 18) + (w << 16);
    const char* wt2a = (const char*)ws + (1 << 18) + (w << 16);
    const char* wt2b = (const char*)ws + (2 << 18) + (w << 16);
    const char* wt3  = (const char*)ws + (3 << 18) + (w << 16);

    __shared__ float pexA[2][2][4][H];      // [par][sample][wave][col], 16 KB each
    __shared__ float pexB[2][2][4][H];
    __shared__ float pexC[2][2][4][H];
    __shared__ float wred[4][2][10];

    int mc, mon, mps;
    mask_params(j, mc, mon, mps);
    int ph = (mc - (mps % mc)) % mc;

    const float bs1 = b_i2h1[j] + b_h2h1[j];
    const float bs2 = b_i2h2[j] + b_h2h2[j];
    const float bs3 = b_i2h3[j];
    const float wi1 = w_i2h1[j];

    float mem1[2] = {0.f,0.f}, mem2[2] = {0.f,0.f}, mem3[2] = {0.f,0.f};
    float sp1 [2] = {0.f,0.f}, sp2 [2] = {0.f,0.f}, sp3 [2] = {0.f,0.f};
    u64 b1s0 = 0ull, b1s1 = 0ull;      // L1 spike ballots (prev slot), per sample
    u64 b2s0 = 0ull, b2s1 = 0ull;      // L2 spike ballots (prev slot), per sample
    int mb_d1 = 0, mb_d2 = 0;
    float cnt[2] = {0.f, 0.f};         // sum_t spk3 per sample (out = wo·cnt)

    __syncthreads();

    for (int sl = 0; sl < T_STEPS + 2; sl++) {
        const int par  = sl & 1;
        const int mbit = (ph < mon) ? 1 : 0;
        const bool runL1 = (sl < T_STEPS);
        const bool runL2 = (sl >= 1) && (sl <= T_STEPS);
        const bool runL3 = (sl >= 2);

        // Broadcast x loads for this slot (issued early; consumed after the
        // barrier -> latency hidden under the whole load region).
        float xq0 = 0.f, xq1 = 0.f;
        if (runL1) {
            xq0 = x[(size_t)s0 * T_STEPS + sl];
            xq1 = x[(size_t)(s0 + 1) * T_STEPS + sl];
        }

        // ======== union load region: each row fetched once, both samples ====
        float4 aA0={0,0,0,0}, aA1={0,0,0,0}, aBa0={0,0,0,0}, aBa1={0,0,0,0};
        float4 aBb0={0,0,0,0}, aBb1={0,0,0,0}, aC0={0,0,0,0}, aC1={0,0,0,0};
        consume_pair_2s(wt1,  wt2a, b1s0, b1s1, l16, aA0, aA1, aBa0, aBa1);
        consume_pair_2s(wt2b, wt3,  b2s0, b2s1, l16, aBb0, aBb1, aC0, aC1);
        float4 aB0, aB1;
        aB0.x = aBa0.x + aBb0.x; aB0.y = aBa0.y + aBb0.y;
        aB0.z = aBa0.z + aBb0.z; aB0.w = aBa0.w + aBb0.w;
        aB1.x = aBa1.x + aBb1.x; aB1.y = aBa1.y + aBb1.y;
        aB1.z = aBa1.z + aBb1.z; aB1.w = aBa1.w + aBb1.w;
        if (runL1) {
            ((float4*)pexA[par][0][w])[lane] = aA0;
            ((float4*)pexA[par][1][w])[lane] = aA1;
        }
        if (runL2) {
            ((float4*)pexB[par][0][w])[lane] = aB0;
            ((float4*)pexB[par][1][w])[lane] = aB1;
        }
        if (runL3) {
            ((float4*)pexC[par][0][w])[lane] = aC0;
            ((float4*)pexC[par][1][w])[lane] = aC1;
        }
        __syncthreads();                           // ONE barrier per slot

        // ======== update region: three upds x two samples ========
        if (runL1) {                               // L1 at time sl
            {
                float hs = (pexA[par][0][0][j] + pexA[par][0][1][j])
                         + (pexA[par][0][2][j] + pexA[par][0][3][j]);
                float h1 = hs + fmaf(xq0, wi1, bs1);
                upd(mem1[0], sp1[0], h1, mbit);
            }
            {
                float hs = (pexA[par][1][0][j] + pexA[par][1][1][j])
                         + (pexA[par][1][2][j] + pexA[par][1][3][j]);
                float h1 = hs + fmaf(xq1, wi1, bs1);
                upd(mem1[1], sp1[1], h1, mbit);
            }
            b1s0 = __ballot(sp1[0] != 0.0f);
            b1s1 = __ballot(sp1[1] != 0.0f);
        }
        if (runL2) {                               // L2 at time sl-1
            #pragma unroll
            for (int sp = 0; sp < 2; sp++) {
                float hs = (pexB[par][sp][0][j] + pexB[par][sp][1][j])
                         + (pexB[par][sp][2][j] + pexB[par][sp][3][j]);
                upd(mem2[sp], sp2[sp], hs + bs2, mb_d1);
            }
            b2s0 = __ballot(sp2[0] != 0.0f);
            b2s1 = __ballot(sp2[1] != 0.0f);
        }
        if (runL3) {                               // L3 at time sl-2
            #pragma unroll
            for (int sp = 0; sp < 2; sp++) {
                float hs = (pexC[par][sp][0][j] + pexC[par][sp][1][j])
                         + (pexC[par][sp][2][j] + pexC[par][sp][3][j]);
                upd(mem3[sp], sp3[sp], hs + bs3, mb_d2);
                cnt[sp] += sp3[sp];
            }
        }
        mb_d2 = mb_d1; mb_d1 = mbit;
        ph++; if (ph == mc) ph = 0;
        // pex write-after-read safety: writes of pex[par] at slot sl+2 occur
        // after BAR(sl+1); reads at slot sl occur before BAR(sl+1) — safe.
    }

    // ---- output: out[s][i] = (sum_j w_h2o3[i][j]*cnt_j)/784 + b[i]
    #pragma unroll
    for (int i = 0; i < 10; i++) {
        float wo_i = w_h2o3[i * H + j];
        #pragma unroll
        for (int sp = 0; sp < 2; sp++) {
            float v = cnt[sp] * wo_i;
            for (int off = 32; off; off >>= 1) v += __shfl_down(v, off, 64);
            if (lane == 0) wred[w][sp][i] = v;
        }
    }
    __syncthreads();
    if (tid < 20) {
        int sp = tid / 10, i = tid % 10;
        float sum = (wred[0][sp][i] + wred[1][sp][i])
                  + (wred[2][sp][i] + wred[3][sp][i]);
        out[(size_t)(s0 + sp) * 10 + i] = sum / 784.0f + b_h2o3[i];
    }
}

extern "C" void kernel_launch(void* const* d_in, const int* in_sizes, int n_in,
                              void* d_out, int out_size, void* d_ws, size_t ws_size,
                              hipStream_t stream) {
    (void)in_sizes; (void)n_in; (void)ws_size; (void)out_size;
    const float* x      = (const float*)d_in[0];
    const float* w_i2h1 = (const float*)d_in[1];
    const float* b_i2h1 = (const float*)d_in[2];
    const float* w_h2h1 = (const float*)d_in[3];
    const float* b_h2h1 = (const float*)d_in[4];
    const float* w_i2h2 = (const float*)d_in[5];
    const float* b_i2h2 = (const float*)d_in[6];
    const float* w_h2h2 = (const float*)d_in[7];
    const float* b_h2h2 = (const float*)d_in[8];
    const float* w_i2h3 = (const float*)d_in[9];
    const float* b_i2h3 = (const float*)d_in[10];
    const float* w_h2o3 = (const float*)d_in[11];
    const float* b_h2o3 = (const float*)d_in[12];
    float* ws = (float*)d_ws;   // 4 * 256 KB = 1 MB

    prep_transpose<<<64, 256, 0, stream>>>(w_h2h1, w_i2h2, w_h2h2, w_i2h3, ws);
    srnn_kernel<<<NBLK, NTHR, 0, stream>>>(x,
        w_i2h1, b_i2h1, b_h2h1,
        b_i2h2, b_h2h2, b_i2h3,
        w_h2o3, b_h2o3, ws,
        (float*)d_out);
}

// Round 18
// 1855.858 us; speedup vs baseline: 1.1330x; 1.1330x over previous
//
#include <hip/hip_runtime.h>
#include <stdint.h>

#define T_STEPS 784
#define H 256
#define NBLK 256        // 2 samples per block, 1 block/CU, 8 waves/CU
#define NTHR 512        // 8 waves; wave w owns rows AND neurons [32w, 32w+32)

typedef unsigned long long u64;

// Per-neuron mask parameters, replicating numpy linspace/ceil/round in float64.
__device__ __forceinline__ void mask_params(int j, int& c, int& on, int& ps) {
    const double stepc = (8.0 - 4.0) / 255.0;
    const double stepd = (0.9 - 0.1) / 255.0;
    const double stepp = 4.0 / 255.0;
    double cyc = (j == 255) ? 8.0 : __dadd_rn(__dmul_rn((double)j, stepc), 4.0);
    c = (int)ceil(cyc);
    double dc  = (j == 255) ? 0.9 : __dadd_rn(__dmul_rn((double)j, stepd), 0.1);
    on = (int)ceil(__dmul_rn(dc, (double)c));
    double psd = (j == 255) ? 4.0 : __dmul_rn((double)j, stepp);
    ps = (int)rint(psd);
}

__device__ __forceinline__ void fmac4(float4& a, float f, const float4& w) {
    a.x = fmaf(f, w.x, a.x); a.y = fmaf(f, w.y, a.y);
    a.z = fmaf(f, w.z, a.z); a.w = fmaf(f, w.w, a.w);
}

#define SELF(m,k) ((((m) >> (k)) & 1ull) ? 1.0f : 0.0f)

// Union 2-sample paired consume: one union mask drives TWO matrices; each
// loaded row is applied to BOTH samples via SGPR-select fmacs (f in {0,1};
// fmaf(0,w,a)==a exactly). Straight-line 16-load batches; binary tail.
#define APPLY2(ki, xi, yi)                                         \
    {   float f0 = SELF(m0, ki), f1 = SELF(m1, ki);                \
        fmac4(aX0, f0, xi); fmac4(aX1, f1, xi);                    \
        fmac4(aY0, f0, yi); fmac4(aY1, f1, yi); }

__device__ __forceinline__ void consume_pair_2s(const char* __restrict__ bX,
                                                const char* __restrict__ bY,
                                                u64 m0, u64 m1, int l16,
                                                float4& aX0, float4& aX1,
                                                float4& aY0, float4& aY1) {
    u64 u = m0 | m1;
    int n = __popcll(u);
    while (n >= 8) {
        int k0=__builtin_ctzll(u); u&=u-1; int k1=__builtin_ctzll(u); u&=u-1;
        int k2=__builtin_ctzll(u); u&=u-1; int k3=__builtin_ctzll(u); u&=u-1;
        int k4=__builtin_ctzll(u); u&=u-1; int k5=__builtin_ctzll(u); u&=u-1;
        int k6=__builtin_ctzll(u); u&=u-1; int k7=__builtin_ctzll(u); u&=u-1;
        float4 x0 = *(const float4*)(bX + (k0<<10) + l16);
        float4 x1 = *(const float4*)(bX + (k1<<10) + l16);
        float4 x2 = *(const float4*)(bX + (k2<<10) + l16);
        float4 x3 = *(const float4*)(bX + (k3<<10) + l16);
        float4 x4 = *(const float4*)(bX + (k4<<10) + l16);
        float4 x5 = *(const float4*)(bX + (k5<<10) + l16);
        float4 x6 = *(const float4*)(bX + (k6<<10) + l16);
        float4 x7 = *(const float4*)(bX + (k7<<10) + l16);
        float4 y0 = *(const float4*)(bY + (k0<<10) + l16);
        float4 y1 = *(const float4*)(bY + (k1<<10) + l16);
        float4 y2 = *(const float4*)(bY + (k2<<10) + l16);
        float4 y3 = *(const float4*)(bY + (k3<<10) + l16);
        float4 y4 = *(const float4*)(bY + (k4<<10) + l16);
        float4 y5 = *(const float4*)(bY + (k5<<10) + l16);
        float4 y6 = *(const float4*)(bY + (k6<<10) + l16);
        float4 y7 = *(const float4*)(bY + (k7<<10) + l16);
        APPLY2(k0, x0, y0); APPLY2(k1, x1, y1);
        APPLY2(k2, x2, y2); APPLY2(k3, x3, y3);
        APPLY2(k4, x4, y4); APPLY2(k5, x5, y5);
        APPLY2(k6, x6, y6); APPLY2(k7, x7, y7);
        n -= 8;
    }
    if (n & 4) {
        int k0=__builtin_ctzll(u); u&=u-1; int k1=__builtin_ctzll(u); u&=u-1;
        int k2=__builtin_ctzll(u); u&=u-1; int k3=__builtin_ctzll(u); u&=u-1;
        float4 x0 = *(const float4*)(bX + (k0<<10) + l16);
        float4 x1 = *(const float4*)(bX + (k1<<10) + l16);
        float4 x2 = *(const float4*)(bX + (k2<<10) + l16);
        float4 x3 = *(const float4*)(bX + (k3<<10) + l16);
        float4 y0 = *(const float4*)(bY + (k0<<10) + l16);
        float4 y1 = *(const float4*)(bY + (k1<<10) + l16);
        float4 y2 = *(const float4*)(bY + (k2<<10) + l16);
        float4 y3 = *(const float4*)(bY + (k3<<10) + l16);
        APPLY2(k0, x0, y0); APPLY2(k1, x1, y1);
        APPLY2(k2, x2, y2); APPLY2(k3, x3, y3);
    }
    if (n & 2) {
        int k0=__builtin_ctzll(u); u&=u-1; int k1=__builtin_ctzll(u); u&=u-1;
        float4 x0 = *(const float4*)(bX + (k0<<10) + l16);
        float4 x1 = *(const float4*)(bX + (k1<<10) + l16);
        float4 y0 = *(const float4*)(bY + (k0<<10) + l16);
        float4 y1 = *(const float4*)(bY + (k1<<10) + l16);
        APPLY2(k0, x0, y0); APPLY2(k1, x1, y1);
    }
    if (n & 1) {
        int k0 = __builtin_ctzll(u);
        float4 x0 = *(const float4*)(bX + (k0<<10) + l16);
        float4 y0 = *(const float4*)(bY + (k0<<10) + l16);
        APPLY2(k0, x0, y0);
    }
}

__device__ __forceinline__ void upd(float& mem, float& sp, float h, int mbit) {
    float nm = fmaf(mem * 0.5f, (1.0f - sp), h);
    mem = mbit ? nm : mem;
    sp  = (mbit && (mem > 0.5f)) ? 1.0f : 0.0f;
}

// Tiled transpose of the 4 weight matrices into ws: WT[k][j] = W[j][k].
__global__ __launch_bounds__(256)
void prep_transpose(const float* __restrict__ w1, const float* __restrict__ w2a,
                    const float* __restrict__ w2b, const float* __restrict__ w3,
                    float* __restrict__ ws)
{
    __shared__ float tile[64][65];
    const int bid = blockIdx.x;                 // 64 blocks: m(4) x kt(4) x jt(4)
    const int m  = bid >> 4;
    const int kt = (bid >> 2) & 3;
    const int jt = bid & 3;
    const float* src = (m == 0) ? w1 : (m == 1) ? w2a : (m == 2) ? w2b : w3;
    float* dst = ws + (size_t)m * H * H;
    const int tid = threadIdx.x;
    const int c = tid & 63, r4 = tid >> 6;
    #pragma unroll
    for (int rr = 0; rr < 16; rr++) {
        int r = r4 * 16 + rr;
        tile[r][c] = src[(size_t)(jt * 64 + r) * H + kt * 64 + c];
    }
    __syncthreads();
    #pragma unroll
    for (int rr = 0; rr < 16; rr++) {
        int r = r4 * 16 + rr;
        dst[(size_t)(kt * 64 + r) * H + jt * 64 + c] = tile[c][r];
    }
}

// Systolic slots: slot sl computes L1(sl), L2(sl-1), L3(sl-2) for TWO samples.
// 8 waves; wave w owns rows AND neurons [32w,32w+32): lanes 0-31 = neurons,
// lanes 32-63 duplicate them, so each sample's ballot low-u32 IS the wave's
// register-resident row gate. Union row-fetch serves both samples. ONE
// barrier per slot; pex double-buffered by parity.
__global__ __launch_bounds__(NTHR, 2)
void srnn_kernel(const float* __restrict__ x,
                 const float* __restrict__ w_i2h1, const float* __restrict__ b_i2h1,
                 const float* __restrict__ b_h2h1,
                 const float* __restrict__ b_i2h2, const float* __restrict__ b_h2h2,
                 const float* __restrict__ b_i2h3,
                 const float* __restrict__ w_h2o3, const float* __restrict__ b_h2o3,
                 const float* __restrict__ ws,     // WT1 | WT2a | WT2b | WT3
                 float* __restrict__ out)
{
    const int tid  = threadIdx.x;
    const int lane = tid & 63;
    const int w    = tid >> 6;              // wave id = 32-row/32-neuron group
    const int j    = w * 32 + (lane & 31);  // this thread's neuron (duplicated)
    const int l16  = lane * 16;             // byte offset into each row
    const int s0   = blockIdx.x * 2;        // first of this block's two samples

    // Wave's row-slice base per matrix: rows [32w, 32w+32), 32KB per slice.
    const char* wt1  = (const char*)ws + (0 << 18) + (w << 15);
    const char* wt2a = (const char*)ws + (1 << 18) + (w << 15);
    const char* wt2b = (const char*)ws + (2 << 18) + (w << 15);
    const char* wt3  = (const char*)ws + (3 << 18) + (w << 15);

    __shared__ float pexA[2][2][8][H];      // [par][sample][wave][col], 16 KB each
    __shared__ float pexB[2][2][8][H];
    __shared__ float pexC[2][2][8][H];
    __shared__ float wred[8][2][10];

    int mc, mon, mps;
    mask_params(j, mc, mon, mps);
    int ph = (mc - (mps % mc)) % mc;

    const float bs1 = b_i2h1[j] + b_h2h1[j];
    const float bs2 = b_i2h2[j] + b_h2h2[j];
    const float bs3 = b_i2h3[j];
    const float wi1 = w_i2h1[j];

    float mem1[2] = {0.f,0.f}, mem2[2] = {0.f,0.f}, mem3[2] = {0.f,0.f};
    float sp1 [2] = {0.f,0.f}, sp2 [2] = {0.f,0.f}, sp3 [2] = {0.f,0.f};
    u64 b1s0 = 0ull, b1s1 = 0ull;      // L1 row gates (prev slot), per sample
    u64 b2s0 = 0ull, b2s1 = 0ull;      // L2 row gates (prev slot), per sample
    int mb_d1 = 0, mb_d2 = 0;
    float cnt[2] = {0.f, 0.f};         // sum_t spk3 per sample (out = wo·cnt)

    __syncthreads();

    for (int sl = 0; sl < T_STEPS + 2; sl++) {
        const int par  = sl & 1;
        const int mbit = (ph < mon) ? 1 : 0;
        const bool runL1 = (sl < T_STEPS);
        const bool runL2 = (sl >= 1) && (sl <= T_STEPS);
        const bool runL3 = (sl >= 2);

        // Broadcast x loads for this slot (issued early; consumed after the
        // load region -> latency hidden).
        float xq0 = 0.f, xq1 = 0.f;
        if (runL1) {
            xq0 = x[(size_t)s0 * T_STEPS + sl];
            xq1 = x[(size_t)(s0 + 1) * T_STEPS + sl];
        }

        // ======== union load region: each row fetched once, both samples ====
        float4 aA0={0,0,0,0}, aA1={0,0,0,0}, aBa0={0,0,0,0}, aBa1={0,0,0,0};
        float4 aBb0={0,0,0,0}, aBb1={0,0,0,0}, aC0={0,0,0,0}, aC1={0,0,0,0};
        consume_pair_2s(wt1,  wt2a, b1s0, b1s1, l16, aA0, aA1, aBa0, aBa1);
        consume_pair_2s(wt2b, wt3,  b2s0, b2s1, l16, aBb0, aBb1, aC0, aC1);
        float4 aB0, aB1;
        aB0.x = aBa0.x + aBb0.x; aB0.y = aBa0.y + aBb0.y;
        aB0.z = aBa0.z + aBb0.z; aB0.w = aBa0.w + aBb0.w;
        aB1.x = aBa1.x + aBb1.x; aB1.y = aBa1.y + aBb1.y;
        aB1.z = aBa1.z + aBb1.z; aB1.w = aBa1.w + aBb1.w;
        if (runL1) {
            ((float4*)pexA[par][0][w])[lane] = aA0;
            ((float4*)pexA[par][1][w])[lane] = aA1;
        }
        if (runL2) {
            ((float4*)pexB[par][0][w])[lane] = aB0;
            ((float4*)pexB[par][1][w])[lane] = aB1;
        }
        if (runL3) {
            ((float4*)pexC[par][0][w])[lane] = aC0;
            ((float4*)pexC[par][1][w])[lane] = aC1;
        }
        __syncthreads();                           // ONE barrier per slot

        // ======== update region: three upds x two samples ========
        if (runL1) {                               // L1 at time sl
            {
                float hs = ((pexA[par][0][0][j] + pexA[par][0][1][j])
                          + (pexA[par][0][2][j] + pexA[par][0][3][j]))
                         + ((pexA[par][0][4][j] + pexA[par][0][5][j])
                          + (pexA[par][0][6][j] + pexA[par][0][7][j]));
                float h1 = hs + fmaf(xq0, wi1, bs1);
                upd(mem1[0], sp1[0], h1, mbit);
            }
            {
                float hs = ((pexA[par][1][0][j] + pexA[par][1][1][j])
                          + (pexA[par][1][2][j] + pexA[par][1][3][j]))
                         + ((pexA[par][1][4][j] + pexA[par][1][5][j])
                          + (pexA[par][1][6][j] + pexA[par][1][7][j]));
                float h1 = hs + fmaf(xq1, wi1, bs1);
                upd(mem1[1], sp1[1], h1, mbit);
            }
            b1s0 = __ballot(sp1[0] != 0.0f) & 0xFFFFFFFFull;
            b1s1 = __ballot(sp1[1] != 0.0f) & 0xFFFFFFFFull;
        }
        if (runL2) {                               // L2 at time sl-1
            #pragma unroll
            for (int sp = 0; sp < 2; sp++) {
                float hs = ((pexB[par][sp][0][j] + pexB[par][sp][1][j])
                          + (pexB[par][sp][2][j] + pexB[par][sp][3][j]))
                         + ((pexB[par][sp][4][j] + pexB[par][sp][5][j])
                          + (pexB[par][sp][6][j] + pexB[par][sp][7][j]));
                upd(mem2[sp], sp2[sp], hs + bs2, mb_d1);
            }
            b2s0 = __ballot(sp2[0] != 0.0f) & 0xFFFFFFFFull;
            b2s1 = __ballot(sp2[1] != 0.0f) & 0xFFFFFFFFull;
        }
        if (runL3) {                               // L3 at time sl-2
            #pragma unroll
            for (int sp = 0; sp < 2; sp++) {
                float hs = ((pexC[par][sp][0][j] + pexC[par][sp][1][j])
                          + (pexC[par][sp][2][j] + pexC[par][sp][3][j]))
                         + ((pexC[par][sp][4][j] + pexC[par][sp][5][j])
                          + (pexC[par][sp][6][j] + pexC[par][sp][7][j]));
                upd(mem3[sp], sp3[sp], hs + bs3, mb_d2);
                cnt[sp] += sp3[sp];
            }
        }
        mb_d2 = mb_d1; mb_d1 = mbit;
        ph++; if (ph == mc) ph = 0;
        // pex write-after-read safety: writes of pex[par] at slot sl+2 occur
        // after BAR(sl+1); reads at slot sl occur before BAR(sl+1) — safe.
    }

    // ---- output: out[s][i] = (sum_j w_h2o3[i][j]*cnt_j)/784 + b[i]
    // Lanes 32-63 duplicate neurons: reduce over lanes 0-31 only.
    #pragma unroll
    for (int i = 0; i < 10; i++) {
        float wo_i = w_h2o3[i * H + j];
        #pragma unroll
        for (int sp = 0; sp < 2; sp++) {
            float v = cnt[sp] * wo_i;
            for (int off = 16; off; off >>= 1) v += __shfl_down(v, off, 32);
            if (lane == 0) wred[w][sp][i] = v;
        }
    }
    __syncthreads();
    if (tid < 20) {
        int sp = tid / 10, i = tid % 10;
        float sum = ((wred[0][sp][i] + wred[1][sp][i])
                   + (wred[2][sp][i] + wred[3][sp][i]))
                  + ((wred[4][sp][i] + wred[5][sp][i])
                   + (wred[6][sp][i] + wred[7][sp][i]));
        out[(size_t)(s0 + sp) * 10 + i] = sum / 784.0f + b_h2o3[i];
    }
}

extern "C" void kernel_launch(void* const* d_in, const int* in_sizes, int n_in,
                              void* d_out, int out_size, void* d_ws, size_t ws_size,
                              hipStream_t stream) {
    (void)in_sizes; (void)n_in; (void)ws_size; (void)out_size;
    const float* x      = (const float*)d_in[0];
    const float* w_i2h1 = (const float*)d_in[1];
    const float* b_i2h1 = (const float*)d_in[2];
    const float* w_h2h1 = (const float*)d_in[3];
    const float* b_h2h1 = (const float*)d_in[4];
    const float* w_i2h2 = (const float*)d_in[5];
    const float* b_i2h2 = (const float*)d_in[6];
    const float* w_h2h2 = (const float*)d_in[7];
    const float* b_h2h2 = (const float*)d_in[8];
    const float* w_i2h3 = (const float*)d_in[9];
    const float* b_i2h3 = (const float*)d_in[10];
    const float* w_h2o3 = (const float*)d_in[11];
    const float* b_h2o3 = (const float*)d_in[12];
    float* ws = (float*)d_ws;   // 4 * 256 KB = 1 MB

    prep_transpose<<<64, 256, 0, stream>>>(w_h2h1, w_i2h2, w_h2h2, w_i2h3, ws);
    srnn_kernel<<<NBLK, NTHR, 0, stream>>>(x,
        w_i2h1, b_i2h1, b_h2h1,
        b_i2h2, b_h2h2, b_i2h3,
        w_h2o3, b_h2o3, ws,
        (float*)d_out);
}

// Round 19
// 1736.635 us; speedup vs baseline: 1.2108x; 1.0687x over previous
//
#include <hip/hip_runtime.h>
#include <stdint.h>

#define T_STEPS 784
#define H 256
#define NBLK 512        // 1 sample per block, 2 blocks/CU (16 waves/CU)
#define NTHR 512        // 8 waves; wave w owns rows AND neurons [32w, 32w+32)

typedef unsigned long long u64;
typedef unsigned int u32;

// Per-neuron mask parameters, replicating numpy linspace/ceil/round in float64.
__device__ __forceinline__ void mask_params(int j, int& c, int& on, int& ps) {
    const double stepc = (8.0 - 4.0) / 255.0;
    const double stepd = (0.9 - 0.1) / 255.0;
    const double stepp = 4.0 / 255.0;
    double cyc = (j == 255) ? 8.0 : __dadd_rn(__dmul_rn((double)j, stepc), 4.0);
    c = (int)ceil(cyc);
    double dc  = (j == 255) ? 0.9 : __dadd_rn(__dmul_rn((double)j, stepd), 0.1);
    on = (int)ceil(__dmul_rn(dc, (double)c));
    double psd = (j == 255) ? 4.0 : __dmul_rn((double)j, stepp);
    ps = (int)rint(psd);
}

__device__ __forceinline__ void acc_add(const float4& w, float4& a) {
    a.x += w.x; a.y += w.y; a.z += w.z; a.w += w.w;
}

// Paired sparse accumulate: one gate mask drives TWO matrices (same k rows).
// m: low-32-bit row mask (wave's own ballot low half, register-resident).
// Rows 1KB apart; lane covers 4 cols via l16. Straight-line batches (R11/R12
// lesson: no data-dependent branches inside batches); binary tail.
__device__ __forceinline__ void consume_pair(const char* __restrict__ bX,
                                             const char* __restrict__ bY,
                                             u64 m, int l16,
                                             float4& aX, float4& aY) {
    int n = __popcll(m);
    while (n >= 8) {
        int k0=__builtin_ctzll(m); m&=m-1; int k1=__builtin_ctzll(m); m&=m-1;
        int k2=__builtin_ctzll(m); m&=m-1; int k3=__builtin_ctzll(m); m&=m-1;
        int k4=__builtin_ctzll(m); m&=m-1; int k5=__builtin_ctzll(m); m&=m-1;
        int k6=__builtin_ctzll(m); m&=m-1; int k7=__builtin_ctzll(m); m&=m-1;
        float4 x0 = *(const float4*)(bX + (k0<<10) + l16);
        float4 x1 = *(const float4*)(bX + (k1<<10) + l16);
        float4 x2 = *(const float4*)(bX + (k2<<10) + l16);
        float4 x3 = *(const float4*)(bX + (k3<<10) + l16);
        float4 x4 = *(const float4*)(bX + (k4<<10) + l16);
        float4 x5 = *(const float4*)(bX + (k5<<10) + l16);
        float4 x6 = *(const float4*)(bX + (k6<<10) + l16);
        float4 x7 = *(const float4*)(bX + (k7<<10) + l16);
        float4 y0 = *(const float4*)(bY + (k0<<10) + l16);
        float4 y1 = *(const float4*)(bY + (k1<<10) + l16);
        float4 y2 = *(const float4*)(bY + (k2<<10) + l16);
        float4 y3 = *(const float4*)(bY + (k3<<10) + l16);
        float4 y4 = *(const float4*)(bY + (k4<<10) + l16);
        float4 y5 = *(const float4*)(bY + (k5<<10) + l16);
        float4 y6 = *(const float4*)(bY + (k6<<10) + l16);
        float4 y7 = *(const float4*)(bY + (k7<<10) + l16);
        acc_add(x0, aX); acc_add(x1, aX); acc_add(x2, aX); acc_add(x3, aX);
        acc_add(x4, aX); acc_add(x5, aX); acc_add(x6, aX); acc_add(x7, aX);
        acc_add(y0, aY); acc_add(y1, aY); acc_add(y2, aY); acc_add(y3, aY);
        acc_add(y4, aY); acc_add(y5, aY); acc_add(y6, aY); acc_add(y7, aY);
        n -= 8;
    }
    if (n & 4) {
        int k0=__builtin_ctzll(m); m&=m-1; int k1=__builtin_ctzll(m); m&=m-1;
        int k2=__builtin_ctzll(m); m&=m-1; int k3=__builtin_ctzll(m); m&=m-1;
        float4 x0 = *(const float4*)(bX + (k0<<10) + l16);
        float4 x1 = *(const float4*)(bX + (k1<<10) + l16);
        float4 x2 = *(const float4*)(bX + (k2<<10) + l16);
        float4 x3 = *(const float4*)(bX + (k3<<10) + l16);
        float4 y0 = *(const float4*)(bY + (k0<<10) + l16);
        float4 y1 = *(const float4*)(bY + (k1<<10) + l16);
        float4 y2 = *(const float4*)(bY + (k2<<10) + l16);
        float4 y3 = *(const float4*)(bY + (k3<<10) + l16);
        acc_add(x0, aX); acc_add(x1, aX); acc_add(x2, aX); acc_add(x3, aX);
        acc_add(y0, aY); acc_add(y1, aY); acc_add(y2, aY); acc_add(y3, aY);
    }
    if (n & 2) {
        int k0=__builtin_ctzll(m); m&=m-1; int k1=__builtin_ctzll(m); m&=m-1;
        float4 x0 = *(const float4*)(bX + (k0<<10) + l16);
        float4 x1 = *(const float4*)(bX + (k1<<10) + l16);
        float4 y0 = *(const float4*)(bY + (k0<<10) + l16);
        float4 y1 = *(const float4*)(bY + (k1<<10) + l16);
        acc_add(x0, aX); acc_add(x1, aX);
        acc_add(y0, aY); acc_add(y1, aY);
    }
    if (n & 1) {
        int k0 = __builtin_ctzll(m);
        float4 x0 = *(const float4*)(bX + (k0<<10) + l16);
        float4 y0 = *(const float4*)(bY + (k0<<10) + l16);
        acc_add(x0, aX); acc_add(y0, aY);
    }
}

__device__ __forceinline__ void upd(float& mem, float& sp, float h, int mbit) {
    float nm = fmaf(mem * 0.5f, (1.0f - sp), h);
    mem = mbit ? nm : mem;
    sp  = (mbit && (mem > 0.5f)) ? 1.0f : 0.0f;
}

// Tiled transpose of the 4 weight matrices into ws: WT[k][j] = W[j][k].
__global__ __launch_bounds__(256)
void prep_transpose(const float* __restrict__ w1, const float* __restrict__ w2a,
                    const float* __restrict__ w2b, const float* __restrict__ w3,
                    float* __restrict__ ws)
{
    __shared__ float tile[64][65];
    const int bid = blockIdx.x;                 // 64 blocks: m(4) x kt(4) x jt(4)
    const int m  = bid >> 4;
    const int kt = (bid >> 2) & 3;
    const int jt = bid & 3;
    const float* src = (m == 0) ? w1 : (m == 1) ? w2a : (m == 2) ? w2b : w3;
    float* dst = ws + (size_t)m * H * H;
    const int tid = threadIdx.x;
    const int c = tid & 63, r4 = tid >> 6;
    #pragma unroll
    for (int rr = 0; rr < 16; rr++) {
        int r = r4 * 16 + rr;
        tile[r][c] = src[(size_t)(jt * 64 + r) * H + kt * 64 + c];
    }
    __syncthreads();
    #pragma unroll
    for (int rr = 0; rr < 16; rr++) {
        int r = r4 * 16 + rr;
        dst[(size_t)(kt * 64 + r) * H + jt * 64 + c] = tile[c][r];
    }
}

// Layer-pipelined (systolic) slots: slot sl computes L1(sl), L2(sl-1), L3(sl-2).
// 8 waves; wave w owns rows AND neurons [32w,32w+32): lanes 0-31 = neurons,
// lanes 32-63 duplicate them (identical upds) so the wave's own ballot low-u32
// is its register-resident row gate. One barrier per slot; pex double-buffered.
__global__ __launch_bounds__(NTHR, 4)
void srnn_kernel(const float* __restrict__ x,
                 const float* __restrict__ w_i2h1, const float* __restrict__ b_i2h1,
                 const float* __restrict__ b_h2h1,
                 const float* __restrict__ b_i2h2, const float* __restrict__ b_h2h2,
                 const float* __restrict__ b_i2h3,
                 const float* __restrict__ w_h2o3, const float* __restrict__ b_h2o3,
                 const float* __restrict__ ws,     // WT1 | WT2a | WT2b | WT3
                 float* __restrict__ out)
{
    const int tid  = threadIdx.x;
    const int lane = tid & 63;
    const int w    = tid >> 6;         // wave id = 32-row group = 32-neuron group
    const int j    = w * 32 + (lane & 31);  // this thread's neuron (duplicated)
    const int l16  = lane * 16;        // byte offset into each row (4 cols/lane)
    const int s    = blockIdx.x;       // sample

    // Wave's row-slice base per matrix: rows [32w, 32w+32), 32KB per slice.
    const char* wt1  = (const char*)ws + (0 << 18) + (w << 15);
    const char* wt2a = (const char*)ws + (1 << 18) + (w << 15);
    const char* wt2b = (const char*)ws + (2 << 18) + (w << 15);
    const char* wt3  = (const char*)ws + (3 << 18) + (w << 15);

    __shared__ float xls[T_STEPS];          // 3.1 KB
    __shared__ float pexA[2][8][H];         // double-buffered partials, 16 KB each
    __shared__ float pexB[2][8][H];
    __shared__ float pexC[2][8][H];
    __shared__ float wred[8][10];

    for (int i = tid; i < T_STEPS; i += NTHR)
        xls[i] = x[(size_t)s * T_STEPS + i];

    int mc, mon, mps;
    mask_params(j, mc, mon, mps);
    int ph = (mc - (mps % mc)) % mc;

    const float bs1 = b_i2h1[j] + b_h2h1[j];
    const float bs2 = b_i2h2[j] + b_h2h2[j];
    const float bs3 = b_i2h3[j];
    const float wi1 = w_i2h1[j];

    float mem1 = 0.f, mem2 = 0.f, mem3 = 0.f;
    float sp1 = 0.f, sp2 = 0.f, sp3 = 0.f;
    u64 bal1 = 0ull, bal2 = 0ull;      // prev-slot spike ballots (low-32 = row gate)
    int mb_d1 = 0, mb_d2 = 0;          // mask bits of times slot-1, slot-2
    float cnt = 0.f;                   // sum_t spk3; out = wo·cnt at end (exact)

    __syncthreads();

    for (int sl = 0; sl < T_STEPS + 2; sl++) {
        const int par  = sl & 1;
        const int mbit = (ph < mon) ? 1 : 0;
        const bool runL1 = (sl < T_STEPS);
        const bool runL2 = (sl >= 1) && (sl <= T_STEPS);
        const bool runL3 = (sl >= 2);

        // ======== paired load region (register-resident u32 gates) ========
        float4 accA = {0.f,0.f,0.f,0.f}, accB = {0.f,0.f,0.f,0.f}, accC = {0.f,0.f,0.f,0.f};
        consume_pair(wt1,  wt2a, bal1 & 0xFFFFFFFFull, l16, accA, accB);
        consume_pair(wt2b, wt3,  bal2 & 0xFFFFFFFFull, l16, accB, accC);
        if (runL1) ((float4*)pexA[par][w])[lane] = accA;
        if (runL2) ((float4*)pexB[par][w])[lane] = accB;
        if (runL3) ((float4*)pexC[par][w])[lane] = accC;
        __syncthreads();                           // ONE barrier per slot

        // ======== update region: three upds back-to-back (lane-duplicated) ====
        if (runL1) {                               // L1 at time sl
            float hs = ((pexA[par][0][j] + pexA[par][1][j])
                      + (pexA[par][2][j] + pexA[par][3][j]))
                     + ((pexA[par][4][j] + pexA[par][5][j])
                      + (pexA[par][6][j] + pexA[par][7][j]));
            float h1 = hs + fmaf(xls[sl], wi1, bs1);
            upd(mem1, sp1, h1, mbit);
            bal1 = __ballot(sp1 != 0.0f);
        }
        if (runL2) {                               // L2 at time sl-1
            float hs = ((pexB[par][0][j] + pexB[par][1][j])
                      + (pexB[par][2][j] + pexB[par][3][j]))
                     + ((pexB[par][4][j] + pexB[par][5][j])
                      + (pexB[par][6][j] + pexB[par][7][j]));
            upd(mem2, sp2, hs + bs2, mb_d1);
            bal2 = __ballot(sp2 != 0.0f);
        }
        if (runL3) {                               // L3 at time sl-2
            float hs = ((pexC[par][0][j] + pexC[par][1][j])
                      + (pexC[par][2][j] + pexC[par][3][j]))
                     + ((pexC[par][4][j] + pexC[par][5][j])
                      + (pexC[par][6][j] + pexC[par][7][j]));
            upd(mem3, sp3, hs + bs3, mb_d2);
            cnt += sp3;
        }
        mb_d2 = mb_d1; mb_d1 = mbit;
        ph++; if (ph == mc) ph = 0;
        // pex write-after-read safety: slot sl+2 rewrites pex?[par] only after
        // BAR(sl+1); every wave reads pex?[par] in U(sl) before reaching
        // BAR(sl+1) — double buffer + 1 barrier/slot is race-free (R12 arg).
    }

    // ---- output: out[s][i] = (sum_j w_h2o3[i][j]*cnt_j)/784 + b[i]
    // Lanes 32-63 hold duplicated neurons: reduce over lanes 0-31 only.
    float wo_i;
    #pragma unroll
    for (int i = 0; i < 10; i++) {
        wo_i = w_h2o3[i * H + j];
        float v = cnt * wo_i;
        for (int off = 16; off; off >>= 1) v += __shfl_down(v, off, 32);
        if (lane == 0) wred[w][i] = v;
    }
    __syncthreads();
    if (tid < 10) {
        float sum = ((wred[0][tid] + wred[1][tid]) + (wred[2][tid] + wred[3][tid]))
                  + ((wred[4][tid] + wred[5][tid]) + (wred[6][tid] + wred[7][tid]));
        out[(size_t)s * 10 + tid] = sum / 784.0f + b_h2o3[tid];
    }
}

extern "C" void kernel_launch(void* const* d_in, const int* in_sizes, int n_in,
                              void* d_out, int out_size, void* d_ws, size_t ws_size,
                              hipStream_t stream) {
    (void)in_sizes; (void)n_in; (void)ws_size; (void)out_size;
    const float* x      = (const float*)d_in[0];
    const float* w_i2h1 = (const float*)d_in[1];
    const float* b_i2h1 = (const float*)d_in[2];
    const float* w_h2h1 = (const float*)d_in[3];
    const float* b_h2h1 = (const float*)d_in[4];
    const float* w_i2h2 = (const float*)d_in[5];
    const float* b_i2h2 = (const float*)d_in[6];
    const float* w_h2h2 = (const float*)d_in[7];
    const float* b_h2h2 = (const float*)d_in[8];
    const float* w_i2h3 = (const float*)d_in[9];
    const float* b_i2h3 = (const float*)d_in[10];
    const float* w_h2o3 = (const float*)d_in[11];
    const float* b_h2o3 = (const float*)d_in[12];
    float* ws = (float*)d_ws;   // 4 * 256 KB = 1 MB

    prep_transpose<<<64, 256, 0, stream>>>(w_h2h1, w_i2h2, w_h2h2, w_i2h3, ws);
    srnn_kernel<<<NBLK, NTHR, 0, stream>>>(x,
        w_i2h1, b_i2h1, b_h2h1,
        b_i2h2, b_h2h2, b_i2h3,
        w_h2o3, b_h2o3, ws,
        (float*)d_out);
}